// Round 1
// baseline (19.526 us; speedup 1.0000x reference)
//
#include <hip/hip_runtime.h>

#define QDEG 5          // QSVT polynomial degree (T_1..T_5)
#define KDEG 5          // KAN Chebyshev degree (T_0..T_5)
#define NF   256        // features per row

// fast tanh: 1 - 2/(exp(2x)+1).  Saturates correctly at +-1 for large |x|.
__device__ __forceinline__ float fast_tanh(float x) {
    float e = __expf(2.0f * x);               // v_exp_f32 based
    return 1.0f - __fdividef(2.0f, e + 1.0f); // fast rcp-based divide
}

template<int ROWS>
__global__ void __launch_bounds__(256, 4) qkan_kernel(
    const float* __restrict__ X,      // (B, 256)
    const float* __restrict__ lcu,    // (256, 5)
    const float* __restrict__ sumw,   // (256, 5)
    const float* __restrict__ kanc,   // (1, 256, 6)
    float* __restrict__ out)          // (B, 1)
{
    const int lane = threadIdx.x & 63;
    const int wid  = threadIdx.x >> 6;       // wave within block: 0..3
    const int f0   = lane * 4;               // each lane owns 4 consecutive features

    // ---- one-time per-wave: fold weights into registers --------------------
    // w[j][k]  = lcu[f][k] / sum_k'|lcu[f][k']| * sumw[f][k]   (feeds T_1..T_5(x))
    // c[j][k]  = kan_coeff[f][k]                               (feeds T_0..T_5(z))
    float w[4][QDEG];
    float c[4][KDEG + 1];
    #pragma unroll
    for (int j = 0; j < 4; ++j) {
        const int f = f0 + j;
        float lw[QDEG];
        float l1 = 0.f;
        #pragma unroll
        for (int k = 0; k < QDEG; ++k) {
            lw[k] = lcu[f * QDEG + k];
            l1 += fabsf(lw[k]);
        }
        const float inv = __fdividef(1.0f, l1);
        #pragma unroll
        for (int k = 0; k < QDEG; ++k) w[j][k] = lw[k] * inv * sumw[f * QDEG + k];
        #pragma unroll
        for (int k = 0; k <= KDEG; ++k) c[j][k] = kanc[f * (KDEG + 1) + k];
    }

    // ---- main: ROWS rows per wave ------------------------------------------
    const int row0 = (blockIdx.x * 4 + wid) * ROWS;
    #pragma unroll
    for (int r = 0; r < ROWS; ++r) {
        const int row = row0 + r;
        // coalesced: wave reads the full 1 KB row, 16 B/lane
        const float4 xv = *reinterpret_cast<const float4*>(X + (size_t)row * NF + f0);
        const float xs[4] = {xv.x, xv.y, xv.z, xv.w};

        float acc = 0.f;
        #pragma unroll
        for (int j = 0; j < 4; ++j) {
            const float x = fminf(fmaxf(xs[j], -1.f), 1.f);
            // features = sum_{k=1..5} w[k-1] * T_k(x), via Chebyshev recurrence
            float tprev = 1.f, tcur = x;
            float feat = w[j][0] * x;
            #pragma unroll
            for (int k = 2; k <= QDEG; ++k) {
                const float tnext = fmaf(2.f * x, tcur, -tprev);
                feat = fmaf(w[j][k - 1], tnext, feat);
                tprev = tcur; tcur = tnext;
            }
            const float z = fast_tanh(feat);
            // p = sum_{k=0..5} c[k] * T_k(z)
            float bprev = 1.f, bcur = z;
            float p = fmaf(c[j][1], z, c[j][0]);
            #pragma unroll
            for (int k = 2; k <= KDEG; ++k) {
                const float bnext = fmaf(2.f * z, bcur, -bprev);
                p = fmaf(c[j][k], bnext, p);
                bprev = bcur; bcur = bnext;
            }
            acc += p;
        }

        // wave-64 butterfly reduce
        #pragma unroll
        for (int off = 32; off >= 1; off >>= 1)
            acc += __shfl_xor(acc, off, 64);
        if (lane == 0) out[row] = acc;
    }
}

extern "C" void kernel_launch(void* const* d_in, const int* in_sizes, int n_in,
                              void* d_out, int out_size, void* d_ws, size_t ws_size,
                              hipStream_t stream) {
    const float* X    = (const float*)d_in[0];
    const float* lcu  = (const float*)d_in[1];
    const float* sumw = (const float*)d_in[2];
    const float* kanc = (const float*)d_in[3];
    float* out = (float*)d_out;

    const int B = out_size;                 // 32768 rows (B x 1 output)
    constexpr int ROWS = 4;                 // rows per wave
    const int waves  = B / ROWS;            // 8192 waves
    const int blocks = waves / 4;           // 2048 blocks of 4 waves
    qkan_kernel<ROWS><<<blocks, 256, 0, stream>>>(X, lcu, sumw, kanc, out);
}